// Round 1
// baseline (884.763 us; speedup 1.0000x reference)
//
#include <hip/hip_runtime.h>

#define A_DIM 5
#define B_DIM 32768
#define S_DIM 48
#define HID   256
#define NH    4
#define DH    64
#define TB    32
#define LRELU 0.01f
#define BN_EPS 1e-5f

// ws layout (floats):
//   [0, 7680)      stats partials: 80 blocks x (48 sum + 48 sumsq)
//   [7680, 7920)   mean[240]
//   [7920, 8160)   rstd[240]
//   [8192, 9216)   per-block logits^2 partial sums (1024)

// ---------------- Kernel A: BN partial sums ----------------
// grid 80 = 5 agents x 16 chunks of 2048 rows; block 256
__global__ void stats1_kernel(const float* __restrict__ states, float* __restrict__ ws) {
    const int a = blockIdx.x >> 4;
    const int chunk = blockIdx.x & 15;
    const int t = threadIdx.x;
    const float* base = states + ((size_t)a * B_DIM + (size_t)chunk * 2048) * S_DIM;
    // 2048*48 = 98304 elements, 384 iters of 256; s = (t + 16*i) % 48 cycles with period 3
    float s0 = 0.f, s1 = 0.f, s2 = 0.f, q0 = 0.f, q1 = 0.f, q2 = 0.f;
    for (int i = 0; i < 384; i += 3) {
        float x0 = base[t + (i + 0) * 256];
        float x1 = base[t + (i + 1) * 256];
        float x2 = base[t + (i + 2) * 256];
        s0 += x0; q0 += x0 * x0;
        s1 += x1; q1 += x1 * x1;
        s2 += x2; q2 += x2 * x2;
    }
    __shared__ float lsum[48], lsq[48];
    if (t < 48) { lsum[t] = 0.f; lsq[t] = 0.f; }
    __syncthreads();
    const int sA = t % 48, sB = (t + 16) % 48, sC = (t + 32) % 48;
    atomicAdd(&lsum[sA], s0); atomicAdd(&lsq[sA], q0);
    atomicAdd(&lsum[sB], s1); atomicAdd(&lsq[sB], q1);
    atomicAdd(&lsum[sC], s2); atomicAdd(&lsq[sC], q2);
    __syncthreads();
    if (t < 48) {
        ws[blockIdx.x * 96 + t] = lsum[t];
        ws[blockIdx.x * 96 + 48 + t] = lsq[t];
    }
}

// ---------------- Kernel B: finalize mean/rstd ----------------
__global__ void stats2_kernel(float* __restrict__ ws) {
    const int t = threadIdx.x;
    if (t >= 240) return;
    const int a = t / 48, s = t % 48;
    float sum = 0.f, sq = 0.f;
    for (int c = 0; c < 16; ++c) {
        sum += ws[(a * 16 + c) * 96 + s];
        sq  += ws[(a * 16 + c) * 96 + 48 + s];
    }
    const float mean = sum * (1.f / (float)B_DIM);
    const float var  = sq * (1.f / (float)B_DIM) - mean * mean;
    ws[7680 + t] = mean;
    ws[7920 + t] = rsqrtf(var + BN_EPS);
}

// ---------------- micro GEMM: 2 rows x 8 cols per thread ----------------
// outp/biasp pre-offset by c0. ldo must make (row*ldo + c0) 16B-aligned (ldo=260).
template<int K, bool LEAKY, bool BIAS>
__device__ __forceinline__ void gemm_tile(
    const float* __restrict__ in_lds, int ldi,
    const float* __restrict__ wp, int wstride,
    const float* __restrict__ biasp,
    float* __restrict__ outp, int ldo, int r0)
{
    float acc[2][8];
#pragma unroll
    for (int r = 0; r < 2; ++r)
#pragma unroll
        for (int j = 0; j < 8; ++j) acc[r][j] = 0.f;

#pragma unroll 4
    for (int kk = 0; kk < K; ++kk) {
        const float a0 = in_lds[(r0 + 0) * ldi + kk];
        const float a1 = in_lds[(r0 + 1) * ldi + kk];
        const float4 w0 = *(const float4*)(wp);
        const float4 w1 = *(const float4*)(wp + 4);
        wp += wstride;
        const float w[8] = {w0.x, w0.y, w0.z, w0.w, w1.x, w1.y, w1.z, w1.w};
#pragma unroll
        for (int j = 0; j < 8; ++j) {
            acc[0][j] += a0 * w[j];
            acc[1][j] += a1 * w[j];
        }
    }
#pragma unroll
    for (int r = 0; r < 2; ++r) {
        float v[8];
#pragma unroll
        for (int j = 0; j < 8; ++j) {
            float x = acc[r][j];
            if (BIAS) x += biasp[j];
            if (LEAKY) x = x >= 0.f ? x : LRELU * x;
            v[j] = x;
        }
        float* op = outp + (r0 + r) * ldo;
        *(float4*)(op)     = make_float4(v[0], v[1], v[2], v[3]);
        *(float4*)(op + 4) = make_float4(v[4], v[5], v[6], v[7]);
    }
}

// ---------------- Kernel C: fused main ----------------
// grid 1024 (32 rows each), block 512
__global__ void __launch_bounds__(512)
main_kernel(const float* __restrict__ states,
            const float* __restrict__ W_enc, const float* __restrict__ b_enc,
            const float* __restrict__ W_key, const float* __restrict__ W_sel,
            const float* __restrict__ W_c1,  const float* __restrict__ b_c1,
            const float* __restrict__ W_c2,  const float* __restrict__ b_c2,
            const float* __restrict__ meanrstd,
            float* __restrict__ out, float* __restrict__ sq_parts)
{
    extern __shared__ float lds[];
    float* xn  = lds;              // [32][49]   = 1568
    float* enc = xn  + 32 * 49;    // [32][260]
    float* sel = enc + 32 * 260;   // [32][260]
    float* tmp = sel + 32 * 260;   // [32][260]  (keys / h)

    const int t  = threadIdx.x;
    const int b0 = blockIdx.x * TB;
    const int tr = t >> 5;         // 0..15
    const int tc = t & 31;         // 0..31
    const int r0 = tr * 2;
    const int c0 = tc * 8;
    const float* meanp = meanrstd;
    const float* rstdp = meanrstd + 240;

    float sqacc = 0.f;

    for (int a = 0; a < A_DIM; ++a) {
        // ---- load + batchnorm-normalize this agent's 32x48 tile ----
        {
            const float* sp = states + ((size_t)a * B_DIM + b0) * S_DIM;
            const float* mp = meanp + a * 48;
            const float* rp = rstdp + a * 48;
            for (int i = t; i < TB * S_DIM; i += 512) {
                const int row = i / 48, s = i % 48;
                xn[row * 49 + s] = (sp[i] - mp[s]) * rp[s];
            }
        }
        __syncthreads();

        // ---- enc = leaky(xn @ W_enc + b_enc) ----
        gemm_tile<48, true, true>(xn, 49, W_enc + c0, 256, b_enc + c0, enc + c0, 260, r0);
        __syncthreads();

        if (a == 0) {
            // sel = enc @ W_sel  (4 heads concatenated as N=256)
            {
                const int k = c0 >> 6, d0 = c0 & 63;
                gemm_tile<256, false, false>(enc, 260, W_sel + k * HID * DH + d0, 64,
                                             nullptr, sel + c0, 260, r0);
            }
            __syncthreads();
            // h = leaky(enc @ W_c1 + b_c1) -> tmp
            gemm_tile<256, true, true>(enc, 260, W_c1 + c0, 256, b_c1 + c0, tmp + c0, 260, r0);
            __syncthreads();
            // all_q = h @ W_c2 + b_c2 -> out (N=8)
            if (t < 256) {
                const int row = t >> 3, c = t & 7;
                float acc = 0.f;
                for (int h = 0; h < HID; ++h) acc += tmp[row * 260 + h] * W_c2[h * 8 + c];
                out[(size_t)(b0 + row) * 8 + c] = acc + b_c2[c];
            }
        } else {
            // keys = enc @ W_key -> tmp
            {
                const int k = c0 >> 6, d0 = c0 & 63;
                gemm_tile<256, false, false>(enc, 260, W_key + k * HID * DH + d0, 64,
                                             nullptr, tmp + c0, 260, r0);
            }
            __syncthreads();
            // logits[row][k] = sum_d sel[row][k*64+d] * keys[row][k*64+d]; accumulate l^2
            if (t < 256) {
                const int row = t >> 3, q = t & 7, k = q >> 1, half = q & 1;
                const int base = row * 260 + k * 64 + half * 32;
                float p = 0.f;
                for (int d = 0; d < 32; ++d) p += sel[base + d] * tmp[base + d];
                const float l = p + __shfl_xor(p, 1);
                if (!half) sqacc += l * l;
            }
            __syncthreads();
        }
    }

    // ---- block reduction of sqacc ----
    __syncthreads();
    float* red = xn;  // 1568 floats available, need 512
    red[t] = sqacc;
    __syncthreads();
    for (int s = 256; s > 0; s >>= 1) {
        if (t < s) red[t] += red[t + s];
        __syncthreads();
    }
    if (t == 0) sq_parts[blockIdx.x] = red[0];
}

// ---------------- Kernel D: final reg reduce ----------------
__global__ void reduce_reg_kernel(const float* __restrict__ sq_parts, float* __restrict__ out_reg) {
    __shared__ float red[256];
    const int t = threadIdx.x;
    red[t] = sq_parts[t] + sq_parts[t + 256] + sq_parts[t + 512] + sq_parts[t + 768];
    __syncthreads();
    for (int s = 128; s > 0; s >>= 1) {
        if (t < s) red[t] += red[t + s];
        __syncthreads();
    }
    if (t == 0) out_reg[0] = red[0] * (0.001f / ((float)B_DIM * 4.f));
}

extern "C" void kernel_launch(void* const* d_in, const int* in_sizes, int n_in,
                              void* d_out, int out_size, void* d_ws, size_t ws_size,
                              hipStream_t stream) {
    const float* states = (const float*)d_in[0];
    const float* W_enc  = (const float*)d_in[1];
    const float* b_enc  = (const float*)d_in[2];
    const float* W_key  = (const float*)d_in[3];
    const float* W_sel  = (const float*)d_in[4];
    // d_in[5] = W_val, d_in[6] = b_val : dead code (multiplied by 0.0 in reference)
    const float* W_c1   = (const float*)d_in[7];
    const float* b_c1   = (const float*)d_in[8];
    const float* W_c2   = (const float*)d_in[9];
    const float* b_c2   = (const float*)d_in[10];
    float* out = (float*)d_out;
    float* ws  = (float*)d_ws;

    float* stats_part = ws;          // 7680 floats
    float* meanrstd   = ws + 7680;   // 480 floats
    float* sq_parts   = ws + 8192;   // 1024 floats

    stats1_kernel<<<80, 256, 0, stream>>>(states, stats_part);
    stats2_kernel<<<1, 256, 0, stream>>>(ws);

    const size_t ldsz = (size_t)(32 * 49 + 3 * 32 * 260) * sizeof(float); // ~103.6 KB
    main_kernel<<<1024, 512, ldsz, stream>>>(states, W_enc, b_enc, W_key, W_sel,
                                             W_c1, b_c1, W_c2, b_c2,
                                             meanrstd, out, sq_parts);
    reduce_reg_kernel<<<1, 256, 0, stream>>>(sq_parts, out + (size_t)B_DIM * 8);
}

// Round 2
// 159.616 us; speedup vs baseline: 5.5431x; 5.5431x over previous
//
#include <hip/hip_runtime.h>

#define A_DIM 5
#define B_DIM 32768
#define S_DIM 48
#define HID   256
#define LRELU 0.01f
#define BN_EPS 1e-5f

#define LDX 72    // xn LDS leading dim (bf16 elems), row stride 144B (16B-aligned, banks spread)
#define LDE 264   // enc/sel LDS leading dim, row stride 528B

// ws float layout:
//   [0, 15360)      stats partials: 160 blocks x (48 sum + 48 sq)
//   [15360, 15840)  mean[240], rstd[240]
//   [15872, 16384)  sq_parts[512]
//   float 16384+ :  bf16 swizzled weights (see OFF_*)
#define OFF_ENC 0        // 16384 bf16  (N=256, K=64 padded)
#define OFF_SEL 16384    // 65536 bf16  (N=256, K=256)
#define OFF_KEY 81920    // 65536
#define OFF_C1  147456   // 65536
#define OFF_C2  212992   // 4096 bf16   (N=16 padded, K=256)

typedef __bf16 bf16x8 __attribute__((ext_vector_type(8)));
typedef float  f32x4  __attribute__((ext_vector_type(4)));

__device__ __forceinline__ unsigned short f2bf(float x) {
    unsigned u = __builtin_bit_cast(unsigned, x);
    unsigned r = (u + 0x7FFFu + ((u >> 16) & 1u)) >> 16;
    return (unsigned short)r;
}
__device__ __forceinline__ float bf2f(unsigned short h) {
    return __builtin_bit_cast(float, (unsigned)h << 16);
}
__device__ __forceinline__ f32x4 mfma16(bf16x8 a, bf16x8 b, f32x4 c) {
    return __builtin_amdgcn_mfma_f32_16x16x32_bf16(a, b, c, 0, 0, 0);
}

// ---------------- Kernel A: BN partial sums (160 blocks x 256) ----------------
__global__ void stats1_kernel(const float* __restrict__ states, float* __restrict__ ws) {
    const int a = blockIdx.x >> 5;
    const int chunk = blockIdx.x & 31;
    const int t = threadIdx.x;
    const float* base = states + ((size_t)a * B_DIM + (size_t)chunk * 1024) * S_DIM;
    float s0 = 0.f, s1 = 0.f, s2 = 0.f, q0 = 0.f, q1 = 0.f, q2 = 0.f;
    for (int i = 0; i < 192; i += 3) {
        float x0 = base[t + (i + 0) * 256];
        float x1 = base[t + (i + 1) * 256];
        float x2 = base[t + (i + 2) * 256];
        s0 += x0; q0 += x0 * x0;
        s1 += x1; q1 += x1 * x1;
        s2 += x2; q2 += x2 * x2;
    }
    __shared__ float lsum[48], lsq[48];
    if (t < 48) { lsum[t] = 0.f; lsq[t] = 0.f; }
    __syncthreads();
    const int sA = t % 48, sB = (t + 16) % 48, sC = (t + 32) % 48;
    atomicAdd(&lsum[sA], s0); atomicAdd(&lsq[sA], q0);
    atomicAdd(&lsum[sB], s1); atomicAdd(&lsq[sB], q1);
    atomicAdd(&lsum[sC], s2); atomicAdd(&lsq[sC], q2);
    __syncthreads();
    if (t < 48) {
        ws[blockIdx.x * 96 + t] = lsum[t];
        ws[blockIdx.x * 96 + 48 + t] = lsq[t];
    }
}

// ---------------- Kernel B: finalize mean/rstd ----------------
__global__ void stats2_kernel(float* __restrict__ ws) {
    const int t = threadIdx.x;
    if (t >= 240) return;
    const int a = t / 48, s = t % 48;
    float sum = 0.f, sq = 0.f;
    for (int c = 0; c < 32; ++c) {
        sum += ws[(a * 32 + c) * 96 + s];
        sq  += ws[(a * 32 + c) * 96 + 48 + s];
    }
    const float mean = sum * (1.f / (float)B_DIM);
    const float var  = sq * (1.f / (float)B_DIM) - mean * mean;
    ws[15360 + t] = mean;
    ws[15600 + t] = rsqrtf(var + BN_EPS);
}

// ---------------- Kernel P: weights -> bf16, B-fragment swizzled ----------------
// frag layout: dst[((chunk*KS + ks)*64 + lane)*8 + j] = W[k][n],
//   n = chunk*16 + (lane&15), k = ks*32 + (lane>>4)*8 + j
__global__ void prep_kernel(const float* __restrict__ W_enc, const float* __restrict__ W_key,
                            const float* __restrict__ W_sel, const float* __restrict__ W_c1,
                            const float* __restrict__ W_c2, unsigned short* __restrict__ wswz) {
    const int gid = blockIdx.x * 256 + threadIdx.x;
    float vals[8];
    unsigned short* dst;
    if (gid < 2048) {                       // W_enc: chunks=16, KS=2, K pad 48->64
        const int lid = gid, lane = lid & 63, fi = lid >> 6;
        const int ks = fi & 1, chunk = fi >> 1;
        const int n = (chunk << 4) + (lane & 15), k0 = ks * 32 + ((lane >> 4) << 3);
#pragma unroll
        for (int j = 0; j < 8; ++j) { int k = k0 + j; vals[j] = (k < 48) ? W_enc[k * 256 + n] : 0.f; }
        dst = wswz + OFF_ENC + (size_t)lid * 8;
    } else if (gid < 10240) {               // W_sel cat: chunks=16, KS=8
        const int lid = gid - 2048, lane = lid & 63, fi = lid >> 6;
        const int ks = fi & 7, chunk = fi >> 3;
        const int n = (chunk << 4) + (lane & 15), k0 = ks * 32 + ((lane >> 4) << 3);
        const int head = n >> 6, d = n & 63;
#pragma unroll
        for (int j = 0; j < 8; ++j) { int k = k0 + j; vals[j] = W_sel[(head * 256 + k) * 64 + d]; }
        dst = wswz + OFF_SEL + (size_t)lid * 8;
    } else if (gid < 18432) {               // W_key cat
        const int lid = gid - 10240, lane = lid & 63, fi = lid >> 6;
        const int ks = fi & 7, chunk = fi >> 3;
        const int n = (chunk << 4) + (lane & 15), k0 = ks * 32 + ((lane >> 4) << 3);
        const int head = n >> 6, d = n & 63;
#pragma unroll
        for (int j = 0; j < 8; ++j) { int k = k0 + j; vals[j] = W_key[(head * 256 + k) * 64 + d]; }
        dst = wswz + OFF_KEY + (size_t)lid * 8;
    } else if (gid < 26624) {               // W_c1
        const int lid = gid - 18432, lane = lid & 63, fi = lid >> 6;
        const int ks = fi & 7, chunk = fi >> 3;
        const int n = (chunk << 4) + (lane & 15), k0 = ks * 32 + ((lane >> 4) << 3);
#pragma unroll
        for (int j = 0; j < 8; ++j) { int k = k0 + j; vals[j] = W_c1[k * 256 + n]; }
        dst = wswz + OFF_C1 + (size_t)lid * 8;
    } else if (gid < 27136) {               // W_c2: chunks=1 (N pad 8->16), KS=8
        const int lid = gid - 26624, lane = lid & 63, ks = lid >> 6;
        const int n = lane & 15, k0 = ks * 32 + ((lane >> 4) << 3);
#pragma unroll
        for (int j = 0; j < 8; ++j) { int k = k0 + j; vals[j] = (n < 8) ? W_c2[k * 8 + n] : 0.f; }
        dst = wswz + OFF_C2 + (size_t)lid * 8;
    } else return;
#pragma unroll
    for (int j = 0; j < 8; ++j) dst[j] = f2bf(vals[j]);
}

// K-loop: wave owns cols [w*32, w*32+32) over all 4 row-blocks of M=64
template<int KS, int LDI>
__device__ __forceinline__ void gemm_block(const unsigned short* __restrict__ aL,
                                           const unsigned short* __restrict__ bW,
                                           int l15, int lg, int lane, int w,
                                           f32x4 acc[2][4]) {
#pragma unroll
    for (int ks = 0; ks < KS; ++ks) {
        bf16x8 af[4];
#pragma unroll
        for (int rb = 0; rb < 4; ++rb)
            af[rb] = *(const bf16x8*)(aL + (rb * 16 + l15) * LDI + ks * 32 + lg * 8);
#pragma unroll
        for (int c = 0; c < 2; ++c) {
            const int chunk = w * 2 + c;
            bf16x8 bf = *(const bf16x8*)(bW + ((size_t)(chunk * KS + ks) * 64 + lane) * 8);
#pragma unroll
            for (int rb = 0; rb < 4; ++rb)
                acc[c][rb] = mfma16(af[rb], bf, acc[c][rb]);
        }
    }
}

__device__ __forceinline__ void store_tile(unsigned short* __restrict__ dstL, int wn, int l15, int lg,
                                           const f32x4 acc[2][4], float bias0, float bias1, bool dolrelu) {
#pragma unroll
    for (int c = 0; c < 2; ++c) {
        const float bias = c ? bias1 : bias0;
        const int col = wn + c * 16 + l15;
#pragma unroll
        for (int rb = 0; rb < 4; ++rb)
#pragma unroll
            for (int r = 0; r < 4; ++r) {
                const int row = rb * 16 + lg * 4 + r;
                float v = acc[c][rb][r] + bias;
                if (dolrelu) v = v >= 0.f ? v : LRELU * v;
                dstL[row * LDE + col] = f2bf(v);
            }
    }
}

// ---------------- Kernel C: fused main (512 blocks x 512 threads) ----------------
__global__ void __launch_bounds__(512, 4)
main_kernel(const float* __restrict__ states,
            const float* __restrict__ b_enc, const float* __restrict__ b_c1,
            const float* __restrict__ b_c2,
            const unsigned short* __restrict__ wswz,
            const float* __restrict__ meanrstd,
            float* __restrict__ out, float* __restrict__ sq_parts)
{
    extern __shared__ char smem[];
    unsigned short* xnL  = (unsigned short*)smem;       // 64*72 bf16
    unsigned short* encL = xnL + 64 * LDX;              // 64*264
    unsigned short* selL = encL + 64 * LDE;             // 64*264
    float* pbuf = (float*)(selL + 64 * LDE);            // 8*64 f32

    const int t    = threadIdx.x;
    const int lane = t & 63;
    const int w    = t >> 6;
    const int l15  = lane & 15;
    const int lg   = lane >> 4;
    const int b0   = blockIdx.x * 64;
    const int wn   = w * 32;

    const float benc0 = b_enc[wn + l15], benc1 = b_enc[wn + 16 + l15];
    const float bc10  = b_c1[wn + l15],  bc11  = b_c1[wn + 16 + l15];

    // zero xn K-padding (cols 48..63) once
    for (int i = t; i < 64 * 16; i += 512)
        xnL[(i >> 4) * LDX + 48 + (i & 15)] = 0;

    float sqacc = 0.f;

    for (int a = 0; a < A_DIM; ++a) {
        // ---- load + normalize 64x48 tile -> xn bf16 ----
        {
            const float* sp = states + ((size_t)a * B_DIM + b0) * S_DIM;
            const float* mp = meanrstd + a * 48;
            const float* rp = meanrstd + 240 + a * 48;
            for (int i = t; i < 64 * 48; i += 512) {
                const int row = i / 48, s = i - row * 48;
                xnL[row * LDX + s] = f2bf((sp[i] - mp[s]) * rp[s]);
            }
        }
        __syncthreads();

        // ---- enc = leaky(xn @ W_enc + b_enc) ----
        {
            f32x4 acc[2][4] = {};
            gemm_block<2, LDX>(xnL, wswz + OFF_ENC, l15, lg, lane, w, acc);
            store_tile(encL, wn, l15, lg, acc, benc0, benc1, true);
        }
        __syncthreads();

        if (a == 0) {
            // sel = enc @ W_sel (no bias/act)
            {
                f32x4 acc[2][4] = {};
                gemm_block<8, LDE>(encL, wswz + OFF_SEL, l15, lg, lane, w, acc);
                store_tile(selL, wn, l15, lg, acc, 0.f, 0.f, false);
            }
            // h = leaky(enc @ W_c1 + b_c1), then overwrite encL with h
            {
                f32x4 acc[2][4] = {};
                gemm_block<8, LDE>(encL, wswz + OFF_C1, l15, lg, lane, w, acc);
                __syncthreads();   // everyone done reading encL
                store_tile(encL, wn, l15, lg, acc, bc10, bc11, true);
            }
            __syncthreads();
            // all_q = h @ W_c2 + b_c2 (waves 0..3, N=8 of padded 16)
            if (w < 4) {
                f32x4 q = {};
#pragma unroll
                for (int ks = 0; ks < 8; ++ks) {
                    bf16x8 af = *(const bf16x8*)(encL + (w * 16 + l15) * LDE + ks * 32 + lg * 8);
                    bf16x8 bf = *(const bf16x8*)(wswz + OFF_C2 + ((size_t)(ks * 64 + lane)) * 8);
                    q = mfma16(af, bf, q);
                }
                if (l15 < 8) {
                    const float bq = b_c2[l15];
#pragma unroll
                    for (int r = 0; r < 4; ++r) {
                        const int row = w * 16 + lg * 4 + r;
                        out[(size_t)(b0 + row) * 8 + l15] = q[r] + bq;
                    }
                }
            }
        } else {
            // keys = enc @ W_key ; logits from accumulators
            f32x4 acc[2][4] = {};
            gemm_block<8, LDE>(encL, wswz + OFF_KEY, l15, lg, lane, w, acc);
            float p[4][4];
#pragma unroll
            for (int rb = 0; rb < 4; ++rb)
#pragma unroll
                for (int r = 0; r < 4; ++r) p[rb][r] = 0.f;
#pragma unroll
            for (int c = 0; c < 2; ++c) {
                const int col = wn + c * 16 + l15;
#pragma unroll
                for (int rb = 0; rb < 4; ++rb)
#pragma unroll
                    for (int r = 0; r < 4; ++r) {
                        const int row = rb * 16 + lg * 4 + r;
                        p[rb][r] += bf2f(selL[row * LDE + col]) * acc[c][rb][r];
                    }
            }
#pragma unroll
            for (int m = 1; m < 16; m <<= 1)
#pragma unroll
                for (int rb = 0; rb < 4; ++rb)
#pragma unroll
                    for (int r = 0; r < 4; ++r)
                        p[rb][r] += __shfl_xor(p[rb][r], m);
            if (l15 == 0) {
#pragma unroll
                for (int rb = 0; rb < 4; ++rb)
#pragma unroll
                    for (int r = 0; r < 4; ++r)
                        pbuf[w * 64 + rb * 16 + lg * 4 + r] = p[rb][r];
            }
            __syncthreads();
            if (t < 256) {
                const int row = t & 63, k = t >> 6;
                const float l = pbuf[(2 * k) * 64 + row] + pbuf[(2 * k + 1) * 64 + row];
                sqacc += l * l;
            }
        }
    }

    // ---- block reduction of sqacc ----
    __syncthreads();
    float* redL = (float*)smem;
    redL[t] = sqacc;
    __syncthreads();
    for (int s = 256; s > 0; s >>= 1) {
        if (t < s) redL[t] += redL[t + s];
        __syncthreads();
    }
    if (t == 0) sq_parts[blockIdx.x] = redL[0];
}

// ---------------- Kernel D: final reg reduce ----------------
__global__ void reduce_reg_kernel(const float* __restrict__ sq_parts, float* __restrict__ out_reg) {
    __shared__ float red[256];
    const int t = threadIdx.x;
    red[t] = sq_parts[t] + sq_parts[t + 256];
    __syncthreads();
    for (int s = 128; s > 0; s >>= 1) {
        if (t < s) red[t] += red[t + s];
        __syncthreads();
    }
    if (t == 0) out_reg[0] = red[0] * (0.001f / ((float)B_DIM * 4.f));
}

extern "C" void kernel_launch(void* const* d_in, const int* in_sizes, int n_in,
                              void* d_out, int out_size, void* d_ws, size_t ws_size,
                              hipStream_t stream) {
    const float* states = (const float*)d_in[0];
    const float* W_enc  = (const float*)d_in[1];
    const float* b_enc  = (const float*)d_in[2];
    const float* W_key  = (const float*)d_in[3];
    const float* W_sel  = (const float*)d_in[4];
    // d_in[5]=W_val, d_in[6]=b_val: dead (multiplied by 0.0 in reference)
    const float* W_c1   = (const float*)d_in[7];
    const float* b_c1   = (const float*)d_in[8];
    const float* W_c2   = (const float*)d_in[9];
    const float* b_c2   = (const float*)d_in[10];
    float* out = (float*)d_out;
    float* ws  = (float*)d_ws;

    float* meanrstd = ws + 15360;
    float* sq_parts = ws + 15872;
    unsigned short* wswz = (unsigned short*)(ws + 16384);

    stats1_kernel<<<160, 256, 0, stream>>>(states, ws);
    stats2_kernel<<<1, 256, 0, stream>>>(ws);
    prep_kernel<<<106, 256, 0, stream>>>(W_enc, W_key, W_sel, W_c1, W_c2, wswz);

    const size_t ldsz = (size_t)64 * LDX * 2 + (size_t)64 * LDE * 2 * 2 + 8 * 64 * 4; // 78848 B
    main_kernel<<<512, 512, ldsz, stream>>>(states, b_enc, b_c1, b_c2, wswz,
                                            meanrstd, out, sq_parts);
    reduce_reg_kernel<<<1, 256, 0, stream>>>(sq_parts, out + (size_t)B_DIM * 8);
}

// Round 3
// 134.354 us; speedup vs baseline: 6.5853x; 1.1880x over previous
//
#include <hip/hip_runtime.h>

#define A_DIM 5
#define B_DIM 32768
#define S_DIM 48
#define HID   256
#define LRELU 0.01f
#define BN_EPS 1e-5f

#define LDX 72    // xn LDS leading dim (bf16 elems)
#define LDE 264   // enc/sel LDS leading dim

// ws float layout:
//   [0, 15360)      stats partials: 160 blocks x (48 sum + 48 sq)
//   [15360, 15840)  mean[240], rstd[240]
//   [15872, 16384)  sq_parts[512]
//   float 16384+ :  bf16 swizzled weights
#define OFF_ENC 0        // 2048 frags  (N=256, K=64 padded)
#define OFF_SEL 16384
#define OFF_KEY 81920
#define OFF_C1  147456
#define OFF_C2  212992

typedef __bf16 bf16x8 __attribute__((ext_vector_type(8)));
typedef float  f32x4  __attribute__((ext_vector_type(4)));

__device__ __forceinline__ unsigned short f2bf(float x) {
    unsigned u = __builtin_bit_cast(unsigned, x);
    unsigned r = (u + 0x7FFFu + ((u >> 16) & 1u)) >> 16;
    return (unsigned short)r;
}
__device__ __forceinline__ float bf2f(unsigned short h) {
    return __builtin_bit_cast(float, (unsigned)h << 16);
}
__device__ __forceinline__ f32x4 mfma16(bf16x8 a, bf16x8 b, f32x4 c) {
    return __builtin_amdgcn_mfma_f32_16x16x32_bf16(a, b, c, 0, 0, 0);
}

// ---------------- Kernel A: BN partial sums (160 blocks x 256) ----------------
__global__ void stats1_kernel(const float* __restrict__ states, float* __restrict__ ws) {
    const int a = blockIdx.x >> 5;
    const int chunk = blockIdx.x & 31;
    const int t = threadIdx.x;
    const float* base = states + ((size_t)a * B_DIM + (size_t)chunk * 1024) * S_DIM;
    float s0 = 0.f, s1 = 0.f, s2 = 0.f, q0 = 0.f, q1 = 0.f, q2 = 0.f;
    for (int i = 0; i < 192; i += 3) {
        float x0 = base[t + (i + 0) * 256];
        float x1 = base[t + (i + 1) * 256];
        float x2 = base[t + (i + 2) * 256];
        s0 += x0; q0 += x0 * x0;
        s1 += x1; q1 += x1 * x1;
        s2 += x2; q2 += x2 * x2;
    }
    __shared__ float lsum[48], lsq[48];
    if (t < 48) { lsum[t] = 0.f; lsq[t] = 0.f; }
    __syncthreads();
    const int sA = t % 48, sB = (t + 16) % 48, sC = (t + 32) % 48;
    atomicAdd(&lsum[sA], s0); atomicAdd(&lsq[sA], q0);
    atomicAdd(&lsum[sB], s1); atomicAdd(&lsq[sB], q1);
    atomicAdd(&lsum[sC], s2); atomicAdd(&lsq[sC], q2);
    __syncthreads();
    if (t < 48) {
        ws[blockIdx.x * 96 + t] = lsum[t];
        ws[blockIdx.x * 96 + 48 + t] = lsq[t];
    }
}

// ---------------- Kernel B: finalize mean/rstd ----------------
__global__ void stats2_kernel(float* __restrict__ ws) {
    const int t = threadIdx.x;
    if (t >= 240) return;
    const int a = t / 48, s = t % 48;
    float sum = 0.f, sq = 0.f;
    for (int c = 0; c < 32; ++c) {
        sum += ws[(a * 32 + c) * 96 + s];
        sq  += ws[(a * 32 + c) * 96 + 48 + s];
    }
    const float mean = sum * (1.f / (float)B_DIM);
    const float var  = sq * (1.f / (float)B_DIM) - mean * mean;
    ws[15360 + t] = mean;
    ws[15600 + t] = rsqrtf(var + BN_EPS);
}

// ---------------- Kernel P: weights -> bf16 B-fragments ----------------
__global__ void prep_kernel(const float* __restrict__ W_enc, const float* __restrict__ W_key,
                            const float* __restrict__ W_sel, const float* __restrict__ W_c1,
                            const float* __restrict__ W_c2, unsigned short* __restrict__ wswz) {
    const int gid = blockIdx.x * 256 + threadIdx.x;
    float vals[8];
    unsigned short* dst;
    if (gid < 2048) {                       // W_enc: chunks=16, KS=2, K pad 48->64
        const int lid = gid, lane = lid & 63, fi = lid >> 6;
        const int ks = fi & 1, chunk = fi >> 1;
        const int n = (chunk << 4) + (lane & 15), k0 = ks * 32 + ((lane >> 4) << 3);
#pragma unroll
        for (int j = 0; j < 8; ++j) { int k = k0 + j; vals[j] = (k < 48) ? W_enc[k * 256 + n] : 0.f; }
        dst = wswz + OFF_ENC + (size_t)lid * 8;
    } else if (gid < 10240) {               // W_sel cat
        const int lid = gid - 2048, lane = lid & 63, fi = lid >> 6;
        const int ks = fi & 7, chunk = fi >> 3;
        const int n = (chunk << 4) + (lane & 15), k0 = ks * 32 + ((lane >> 4) << 3);
        const int head = n >> 6, d = n & 63;
#pragma unroll
        for (int j = 0; j < 8; ++j) { int k = k0 + j; vals[j] = W_sel[(head * 256 + k) * 64 + d]; }
        dst = wswz + OFF_SEL + (size_t)lid * 8;
    } else if (gid < 18432) {               // W_key cat
        const int lid = gid - 10240, lane = lid & 63, fi = lid >> 6;
        const int ks = fi & 7, chunk = fi >> 3;
        const int n = (chunk << 4) + (lane & 15), k0 = ks * 32 + ((lane >> 4) << 3);
        const int head = n >> 6, d = n & 63;
#pragma unroll
        for (int j = 0; j < 8; ++j) { int k = k0 + j; vals[j] = W_key[(head * 256 + k) * 64 + d]; }
        dst = wswz + OFF_KEY + (size_t)lid * 8;
    } else if (gid < 26624) {               // W_c1
        const int lid = gid - 18432, lane = lid & 63, fi = lid >> 6;
        const int ks = fi & 7, chunk = fi >> 3;
        const int n = (chunk << 4) + (lane & 15), k0 = ks * 32 + ((lane >> 4) << 3);
#pragma unroll
        for (int j = 0; j < 8; ++j) { int k = k0 + j; vals[j] = W_c1[k * 256 + n]; }
        dst = wswz + OFF_C1 + (size_t)lid * 8;
    } else if (gid < 27136) {               // W_c2: N pad 8->16
        const int lid = gid - 26624, lane = lid & 63, ks = lid >> 6;
        const int n = lane & 15, k0 = ks * 32 + ((lane >> 4) << 3);
#pragma unroll
        for (int j = 0; j < 8; ++j) { int k = k0 + j; vals[j] = (n < 8) ? W_c2[k * 8 + n] : 0.f; }
        dst = wswz + OFF_C2 + (size_t)lid * 8;
    } else return;
#pragma unroll
    for (int j = 0; j < 8; ++j) dst[j] = f2bf(vals[j]);
}

// K-loop with B-fragments loaded from global (L2)
template<int KS>
__device__ __forceinline__ void gemm_block(const unsigned short* __restrict__ aL,
                                           const unsigned short* __restrict__ bW,
                                           int l15, int lg, int lane, int w,
                                           f32x4 acc[2][4]) {
#pragma unroll
    for (int ks = 0; ks < KS; ++ks) {
        bf16x8 af[4];
#pragma unroll
        for (int rb = 0; rb < 4; ++rb)
            af[rb] = *(const bf16x8*)(aL + (rb * 16 + l15) * LDE + ks * 32 + lg * 8);
#pragma unroll
        for (int c = 0; c < 2; ++c) {
            const int chunk = w * 2 + c;
            bf16x8 bf = *(const bf16x8*)(bW + ((size_t)(chunk * KS + ks) * 64 + lane) * 8);
#pragma unroll
            for (int rb = 0; rb < 4; ++rb)
                acc[c][rb] = mfma16(af[rb], bf, acc[c][rb]);
        }
    }
}

__device__ __forceinline__ void store_tile(unsigned short* __restrict__ dstL, int wn, int l15, int lg,
                                           const f32x4 acc[2][4], float bias0, float bias1, bool dolrelu) {
#pragma unroll
    for (int c = 0; c < 2; ++c) {
        const float bias = c ? bias1 : bias0;
        const int col = wn + c * 16 + l15;
#pragma unroll
        for (int rb = 0; rb < 4; ++rb)
#pragma unroll
            for (int r = 0; r < 4; ++r) {
                const int row = rb * 16 + lg * 4 + r;
                float v = acc[c][rb][r] + bias;
                if (dolrelu) v = v >= 0.f ? v : LRELU * v;
                dstL[row * LDE + col] = f2bf(v);
            }
    }
}

// ---------------- Kernel C: fused main (512 blocks x 512 threads) ----------------
__global__ void __launch_bounds__(512, 4)
main_kernel(const float* __restrict__ states,
            const float* __restrict__ b_enc, const float* __restrict__ b_c1,
            const float* __restrict__ b_c2,
            const unsigned short* __restrict__ wswz,
            const float* __restrict__ meanrstd,
            float* __restrict__ out, float* __restrict__ sq_parts)
{
    extern __shared__ char smem[];
    unsigned short* xnL  = (unsigned short*)smem;            // 64*72 bf16   @0
    unsigned short* encL = xnL + 64 * LDX;                   // 64*264       @9216
    unsigned short* selL = encL + 64 * LDE;                  // 64*264       @43008
    float* pbuf = (float*)(selL + 64 * LDE);                 // 8*64 f32     @76800
    float* mrL  = pbuf + 8 * 64;                             // 480 f32      @78848
    float* redF = mrL + 480;                                 // 8 f32        @80768

    const int t    = threadIdx.x;
    const int lane = t & 63;
    const int w    = t >> 6;
    const int l15  = lane & 15;
    const int lg   = lane >> 4;
    const int b0   = blockIdx.x * 64;
    const int wn   = w * 32;

    const float benc0 = b_enc[wn + l15], benc1 = b_enc[wn + 16 + l15];
    const float bc10  = b_c1[wn + l15],  bc11  = b_c1[wn + 16 + l15];

    // hoisted W_enc B-fragments (reused for all 5 agents)
    bf16x8 encB[2][2];
#pragma unroll
    for (int c = 0; c < 2; ++c)
#pragma unroll
        for (int ks = 0; ks < 2; ++ks)
            encB[c][ks] = *(const bf16x8*)(wswz + OFF_ENC +
                           ((size_t)((w * 2 + c) * 2 + ks) * 64 + lane) * 8);

    // prefetch agent 0 states (nt: don't pollute L2)
    float pf[6];
    {
        const float* sp = states + (size_t)b0 * S_DIM;
#pragma unroll
        for (int j = 0; j < 6; ++j) pf[j] = __builtin_nontemporal_load(sp + t + j * 512);
    }
    // mean/rstd -> LDS; zero xn K-pad cols 48..63
    if (t < 480) mrL[t] = meanrstd[t];
    for (int i = t; i < 64 * 16; i += 512)
        xnL[(i >> 4) * LDX + 48 + (i & 15)] = 0;
    __syncthreads();

    // write xn(0)
    {
        const float* mp = mrL, *rp = mrL + 240;
#pragma unroll
        for (int j = 0; j < 6; ++j) {
            const int i = t + j * 512, row = i / 48, s = i - row * 48;
            xnL[row * LDX + s] = f2bf((pf[j] - mp[s]) * rp[s]);
        }
    }
    __syncthreads();

    float sqacc = 0.f;

    for (int a = 0; a < A_DIM; ++a) {
        // issue prefetch for next agent
        float pn[6];
        if (a < 4) {
            const float* sp = states + ((size_t)(a + 1) * B_DIM + b0) * S_DIM;
#pragma unroll
            for (int j = 0; j < 6; ++j) pn[j] = __builtin_nontemporal_load(sp + t + j * 512);
        }

        // ---- enc = leaky(xn @ W_enc + b_enc), B from registers ----
        {
            f32x4 acc[2][4] = {};
#pragma unroll
            for (int ks = 0; ks < 2; ++ks) {
                bf16x8 af[4];
#pragma unroll
                for (int rb = 0; rb < 4; ++rb)
                    af[rb] = *(const bf16x8*)(xnL + (rb * 16 + l15) * LDX + ks * 32 + lg * 8);
#pragma unroll
                for (int c = 0; c < 2; ++c)
#pragma unroll
                    for (int rb = 0; rb < 4; ++rb)
                        acc[c][rb] = mfma16(af[rb], encB[c][ks], acc[c][rb]);
            }
            // fold previous agent's logits^2 accumulation into this phase
            if (a >= 2 && t < 256) {
                const int row = t & 63, k = t >> 6;
                const float l = pbuf[(2 * k) * 64 + row] + pbuf[(2 * k + 1) * 64 + row];
                sqacc += l * l;
            }
            store_tile(encL, wn, l15, lg, acc, benc0, benc1, true);
        }
        __syncthreads();

        if (a == 0) {
            // sel gemm + store; c1 gemm; write xn(1)
            f32x4 acc2[2][4] = {};
            gemm_block<8>(encL, wswz + OFF_SEL, l15, lg, lane, w, acc2);
            store_tile(selL, wn, l15, lg, acc2, 0.f, 0.f, false);
            f32x4 acc3[2][4] = {};
            gemm_block<8>(encL, wswz + OFF_C1, l15, lg, lane, w, acc3);
            {
                const float* mp = mrL + 48, *rp = mrL + 240 + 48;
#pragma unroll
                for (int j = 0; j < 6; ++j) {
                    const int i = t + j * 512, row = i / 48, s = i - row * 48;
                    xnL[row * LDX + s] = f2bf((pn[j] - mp[s]) * rp[s]);
                }
            }
            __syncthreads();
            store_tile(encL, wn, l15, lg, acc3, bc10, bc11, true);   // encL <- h
            __syncthreads();
            // all_q = h @ W_c2 + b_c2
            if (w < 4) {
                f32x4 q = {};
#pragma unroll
                for (int ks = 0; ks < 8; ++ks) {
                    bf16x8 af = *(const bf16x8*)(encL + (w * 16 + l15) * LDE + ks * 32 + lg * 8);
                    bf16x8 bf = *(const bf16x8*)(wswz + OFF_C2 + ((size_t)(ks * 64 + lane)) * 8);
                    q = mfma16(af, bf, q);
                }
                if (l15 < 8) {
                    const float bq = b_c2[l15];
#pragma unroll
                    for (int r = 0; r < 4; ++r) {
                        const int row = w * 16 + lg * 4 + r;
                        __builtin_nontemporal_store(q[r] + bq, &out[(size_t)(b0 + row) * 8 + l15]);
                    }
                }
            }
            __syncthreads();
        } else {
            // keys gemm; logits from accumulators; write xn(a+1)
            f32x4 acc2[2][4] = {};
            gemm_block<8>(encL, wswz + OFF_KEY, l15, lg, lane, w, acc2);
            float p[4][4];
#pragma unroll
            for (int rb = 0; rb < 4; ++rb)
#pragma unroll
                for (int r = 0; r < 4; ++r) p[rb][r] = 0.f;
#pragma unroll
            for (int c = 0; c < 2; ++c) {
                const int col = wn + c * 16 + l15;
#pragma unroll
                for (int rb = 0; rb < 4; ++rb)
#pragma unroll
                    for (int r = 0; r < 4; ++r) {
                        const int row = rb * 16 + lg * 4 + r;
                        p[rb][r] += bf2f(selL[row * LDE + col]) * acc2[c][rb][r];
                    }
            }
#pragma unroll
            for (int m = 1; m < 16; m <<= 1)
#pragma unroll
                for (int rb = 0; rb < 4; ++rb)
#pragma unroll
                    for (int r = 0; r < 4; ++r)
                        p[rb][r] += __shfl_xor(p[rb][r], m);
            if (l15 == 0) {
#pragma unroll
                for (int rb = 0; rb < 4; ++rb)
#pragma unroll
                    for (int r = 0; r < 4; ++r)
                        pbuf[w * 64 + rb * 16 + lg * 4 + r] = p[rb][r];
            }
            if (a < 4) {
                const float* mp = mrL + (a + 1) * 48, *rp = mrL + 240 + (a + 1) * 48;
#pragma unroll
                for (int j = 0; j < 6; ++j) {
                    const int i = t + j * 512, row = i / 48, s = i - row * 48;
                    xnL[row * LDX + s] = f2bf((pn[j] - mp[s]) * rp[s]);
                }
            }
            __syncthreads();
        }
    }

    // last agent's logits^2
    if (t < 256) {
        const int row = t & 63, k = t >> 6;
        const float l = pbuf[(2 * k) * 64 + row] + pbuf[(2 * k + 1) * 64 + row];
        sqacc += l * l;
    }
    // wave reduce, then tiny cross-wave reduce
    float v = sqacc;
#pragma unroll
    for (int m = 1; m < 64; m <<= 1) v += __shfl_xor(v, m);
    if (lane == 0) redF[w] = v;
    __syncthreads();
    if (t == 0) {
        float s = 0.f;
#pragma unroll
        for (int i = 0; i < 8; ++i) s += redF[i];
        sq_parts[blockIdx.x] = s;
    }
}

// ---------------- Kernel D: final reg reduce ----------------
__global__ void reduce_reg_kernel(const float* __restrict__ sq_parts, float* __restrict__ out_reg) {
    __shared__ float red[256];
    const int t = threadIdx.x;
    red[t] = sq_parts[t] + sq_parts[t + 256];
    __syncthreads();
    for (int s = 128; s > 0; s >>= 1) {
        if (t < s) red[t] += red[t + s];
        __syncthreads();
    }
    if (t == 0) out_reg[0] = red[0] * (0.001f / ((float)B_DIM * 4.f));
}

extern "C" void kernel_launch(void* const* d_in, const int* in_sizes, int n_in,
                              void* d_out, int out_size, void* d_ws, size_t ws_size,
                              hipStream_t stream) {
    const float* states = (const float*)d_in[0];
    const float* W_enc  = (const float*)d_in[1];
    const float* b_enc  = (const float*)d_in[2];
    const float* W_key  = (const float*)d_in[3];
    const float* W_sel  = (const float*)d_in[4];
    // d_in[5]=W_val, d_in[6]=b_val: dead (multiplied by 0.0 in reference)
    const float* W_c1   = (const float*)d_in[7];
    const float* b_c1   = (const float*)d_in[8];
    const float* W_c2   = (const float*)d_in[9];
    const float* b_c2   = (const float*)d_in[10];
    float* out = (float*)d_out;
    float* ws  = (float*)d_ws;

    float* meanrstd = ws + 15360;
    float* sq_parts = ws + 15872;
    unsigned short* wswz = (unsigned short*)(ws + 16384);

    stats1_kernel<<<160, 256, 0, stream>>>(states, ws);
    stats2_kernel<<<1, 256, 0, stream>>>(ws);
    prep_kernel<<<106, 256, 0, stream>>>(W_enc, W_key, W_sel, W_c1, W_c2, wswz);

    const size_t ldsz = 64 * LDX * 2 + 64 * LDE * 2 * 2 + (8 * 64 + 480 + 8) * 4; // 80800 B
    main_kernel<<<512, 512, ldsz, stream>>>(states, b_enc, b_c1, b_c2, wswz,
                                            meanrstd, out, sq_parts);
    reduce_reg_kernel<<<1, 256, 0, stream>>>(sq_parts, out + (size_t)B_DIM * 8);
}